// Round 13
// baseline (505.625 us; speedup 1.0000x reference)
//
#include <hip/hip_runtime.h>
#include <stdint.h>

// Problem constants (fixed by setup_inputs): B=8, L=K=2048, D=64
#define BATCH 8
#define NPTS  2048
#define DIM   64
#define VECN  (BATCH*NPTS)   // 16384
#define CHUNK 64             // columns staged per LDS buffer
#define NCHUNK (NPTS/CHUNK)  // 32 (full K per block)

typedef __attribute__((ext_vector_type(8))) short bf16x8;
typedef __attribute__((ext_vector_type(4))) float f32x4;

#define IL2 1.4426950408889634f
#define LN2 0.6931471805599453f

__device__ inline float fexp2(float x) { return __builtin_amdgcn_exp2f(x); }
__device__ inline float flog2(float x) { return __builtin_amdgcn_logf(x); }

// async global->LDS staging (lds dest = uniform base + lane*size; global src per-lane)
__device__ inline void gload_lds16(const void* g, void* l) {
  __builtin_amdgcn_global_load_lds(
      (const __attribute__((address_space(1))) uint32_t*)g,
      (__attribute__((address_space(3))) uint32_t*)l, 16, 0, 0);
}
__device__ inline void gload_lds4(const void* g, void* l) {
  __builtin_amdgcn_global_load_lds(
      (const __attribute__((address_space(1))) uint32_t*)g,
      (__attribute__((address_space(3))) uint32_t*)l, 4, 0, 0);
}

// ---- workspace layout (bytes) ----
static constexpr size_t XB_OFF   = 0;                                   // bf16 x : 2 MB
static constexpr size_t YB_OFF   = (size_t)VECN * DIM * 2;              // bf16 y : 2 MB
static constexpr size_t NX2_OFF  = YB_OFF * 2;                          // ||x||^2 * IL2
static constexpr size_t NY2_OFF  = NX2_OFF + (size_t)VECN * 4;
static constexpr size_t LA2_OFF  = NY2_OFF + (size_t)VECN * 4;          // log2(a)
static constexpr size_t LB2_OFF  = LA2_OFF + (size_t)VECN * 4;          // log2(b)
static constexpr size_t POT_OFF  = LB2_OFF + (size_t)VECN * 4;          // 4 pots
static constexpr size_t NW0_OFF  = POT_OFF + (size_t)4 * VECN * 4;      // nw ping [4][VECN] float2
static constexpr size_t NW1_OFF  = NW0_OFF + (size_t)4 * VECN * 8;      // nw pong
static constexpr size_t FOUT_OFF = NW1_OFF + (size_t)4 * VECN * 8;      // f,g,ge,fe
static constexpr size_t R_OFF    = FOUT_OFF + (size_t)4 * VECN * 4;     // per-row lse (log2) [4][VECN]

__device__ inline ushort f2bf(float f) {
  uint32_t u = __float_as_uint(f);
  u += 0x7fffu + ((u >> 16) & 1u);   // RNE
  return (ushort)(u >> 16);
}

// One wave per row: convert to bf16 + exact f32 squared norm (scaled by IL2).
__global__ void prep_convert(const float* __restrict__ x, const float* __restrict__ y,
                             ushort* __restrict__ xb, ushort* __restrict__ yb,
                             float* __restrict__ nx2, float* __restrict__ ny2) {
  int wid  = (blockIdx.x * blockDim.x + threadIdx.x) >> 6;
  int lane = threadIdx.x & 63;
  const float* src; ushort* dst; float* nrm; int row;
  if (wid < VECN) { src = x; dst = xb; nrm = nx2; row = wid; }
  else            { src = y; dst = yb; nrm = ny2; row = wid - VECN; }
  float v = src[(size_t)row * DIM + lane];
  dst[(size_t)row * DIM + lane] = f2bf(v);
  float sq = v * v;
  #pragma unroll
  for (int off = 32; off; off >>= 1) sq += __shfl_xor(sq, off);
  if (lane == 0) nrm[row] = sq * IL2;
}

// log2-weights, zero pots, init BOTH nw buffers = {V-side norm, V-side log2 weight}
__global__ void prep_vecs(const float* __restrict__ a, const float* __restrict__ b,
                          const float* __restrict__ nx2, const float* __restrict__ ny2,
                          float* __restrict__ la2, float* __restrict__ lb2,
                          float* __restrict__ pot,
                          float2* __restrict__ nw0, float2* __restrict__ nw1) {
  int i = blockIdx.x * blockDim.x + threadIdx.x;
  float l2a = log2f(a[i]);
  float l2b = log2f(b[i]);
  la2[i] = l2a;
  lb2[i] = l2b;
  float nxv = nx2[i], nyv = ny2[i];
  float2 vx = make_float2(nxv, l2a), vy = make_float2(nyv, l2b);
  nw0[i]                    = vx;  nw1[i]                    = vx;  // z0 xx: V=x
  nw0[(size_t)VECN + i]     = vy;  nw1[(size_t)VECN + i]     = vy;  // z1 yy: V=y
  nw0[(size_t)2*VECN + i]   = vy;  nw1[(size_t)2*VECN + i]   = vy;  // z2 xy: V=y
  nw0[(size_t)3*VECN + i]   = vx;  nw1[(size_t)3*VECN + i]   = vx;  // z3 yx: V=x
  #pragma unroll
  for (int j = 0; j < 4; ++j) pot[(size_t)j * VECN + i] = 0.f;
}

// Iteration-0 extrap: online-max flash-LSE over full K, fused finalize epilogue.
// grid: (NPTS/64, BATCH, 4 jobs); block 256 (4 waves, 16 rows each)
__global__ __launch_bounds__(256, 8)
void extrap_online(const ushort* __restrict__ xb, const ushort* __restrict__ yb,
                   const float* __restrict__ nx2, const float* __restrict__ ny2,
                   const float2* __restrict__ nwin, float2* __restrict__ nwout,
                   const float* __restrict__ la2, const float* __restrict__ lb2,
                   float* __restrict__ pot, float* __restrict__ Rarr,
                   float* __restrict__ fouts, int avg) {
  __shared__ char vlds[2][CHUNK * 128];   // 2 x 8 KB, swizzled content
  __shared__ char nwlds[2][CHUNK * 8];    // 2 x 512 B, linear float2

  const int rb    = blockIdx.x;
  const int batch = blockIdx.y;
  const int z     = blockIdx.z;
  const ushort *U, *V; const float *nU2;
  switch (z) {
    case 0:  U = xb; V = xb; nU2 = nx2; break; // xx
    case 1:  U = yb; V = yb; nU2 = ny2; break; // yy
    case 2:  U = xb; V = yb; nU2 = nx2; break; // xy
    default: U = yb; V = xb; nU2 = ny2; break; // yx
  }
  const int lane = threadIdx.x & 63;
  const int w    = threadIdx.x >> 6;
  const int g    = lane >> 4;
  const int c    = lane & 15;
  const int rowbase = rb * 64 + w * 16;

  const ushort* Ub  = U + ((size_t)batch * NPTS + rowbase) * DIM;
  const char*   Vch = (const char*)(V + (size_t)batch * NPTS * DIM); // 128B rows
  const char*   nwch = (const char*)(nwin + (size_t)z * VECN + (size_t)batch * NPTS);

  bf16x8 a0 = *(const bf16x8*)(Ub + (size_t)c * DIM + g * 8);
  bf16x8 a1 = *(const bf16x8*)(Ub + (size_t)c * DIM + 32 + g * 8);

  float nxr2[4];
  #pragma unroll
  for (int r = 0; r < 4; ++r) nxr2[r] = nU2[(size_t)batch * NPTS + rowbase + g * 4 + r];

  const size_t lane_voff = ((size_t)(lane >> 3)) * 128
                         + (size_t)((((lane & 7) ^ (lane >> 3)) << 4));

  float m[4], s[4];
  #pragma unroll
  for (int r = 0; r < 4; ++r) { m[r] = -INFINITY; s[r] = 0.f; }

  auto stage = [&](int p, int ck) {
    const char* gbase = Vch + (size_t)ck * CHUNK * 128;
    #pragma unroll
    for (int i = 0; i < 2; ++i) {
      int j = w * 2 + i;                                  // 1 KB slab = 8 rows
      gload_lds16(gbase + (size_t)j * 1024 + lane_voff, &vlds[p][j * 1024]);
    }
    if (w == 0) {
      const char* gn = nwch + (size_t)ck * CHUNK * 8;
      gload_lds4(gn + lane * 4,       &nwlds[p][0]);
      gload_lds4(gn + 256 + lane * 4, &nwlds[p][256]);
    }
  };

  auto compute = [&](int p) {
    #pragma unroll
    for (int t = 0; t < 2; ++t) {
      const int rr0 = t * 32 + c;
      const int rr1 = rr0 + 16;
      const int x0 = (rr0 & 7) << 4;           // rr1&7 == rr0&7
      const char* pv0 = &vlds[p][rr0 * 128];
      const char* pv1 = &vlds[p][rr1 * 128];
      bf16x8 b0a = *(const bf16x8*)(pv0 + ((g * 16) ^ x0));
      bf16x8 b0b = *(const bf16x8*)(pv0 + ((64 + g * 16) ^ x0));
      bf16x8 b1a = *(const bf16x8*)(pv1 + ((g * 16) ^ x0));
      bf16x8 b1b = *(const bf16x8*)(pv1 + ((64 + g * 16) ^ x0));
      float2 nw0 = *(const float2*)&nwlds[p][rr0 * 8];
      float2 nw1 = *(const float2*)&nwlds[p][rr1 * 8];

      f32x4 acc0 = {0.f, 0.f, 0.f, 0.f}, acc1 = {0.f, 0.f, 0.f, 0.f};
      acc0 = __builtin_amdgcn_mfma_f32_16x16x32_bf16(a0, b0a, acc0, 0, 0, 0);
      acc0 = __builtin_amdgcn_mfma_f32_16x16x32_bf16(a1, b0b, acc0, 0, 0, 0);
      acc1 = __builtin_amdgcn_mfma_f32_16x16x32_bf16(a0, b1a, acc1, 0, 0, 0);
      acc1 = __builtin_amdgcn_mfma_f32_16x16x32_bf16(a1, b1b, acc1, 0, 0, 0);

      #pragma unroll
      for (int r = 0; r < 4; ++r) {
        float d0 = fmaxf(fmaf(-2.f * IL2, acc0[r], nxr2[r] + nw0.x), 0.f);
        float d1 = fmaxf(fmaf(-2.f * IL2, acc1[r], nxr2[r] + nw1.x), 0.f);
        float t0 = nw0.y - d0;
        float t1 = nw1.y - d1;
        float mn = fmaxf(m[r], fmaxf(t0, t1));       // v_max3
        s[r] = fmaf(s[r], fexp2(m[r] - mn), fexp2(t0 - mn) + fexp2(t1 - mn));
        m[r] = mn;
      }
    }
  };

  stage(0, 0);
  __syncthreads();
  int p = 0;
  for (int ck = 0; ck < NCHUNK; ++ck) {
    if (ck < NCHUNK - 1) stage(p ^ 1, ck + 1);   // prefetch in flight during compute
    compute(p);
    __syncthreads();
    p ^= 1;
  }

  #pragma unroll
  for (int r = 0; r < 4; ++r) {
    #pragma unroll
    for (int off = 1; off < 16; off <<= 1) {
      float mo = __shfl_xor(m[r], off);
      float so = __shfl_xor(s[r], off);
      float mn = fmaxf(m[r], mo);
      s[r] = fmaf(s[r], fexp2(m[r] - mn), so * fexp2(mo - mn));
      m[r] = mn;
    }
  }
  if (c == 0) {
    const int cjob = z ^ (z >> 1);                 // 0,1 self; 2<->3
    const float* lw2 = (z & 1) ? lb2 : la2;        // row-side log2 weight
    #pragma unroll
    for (int r = 0; r < 4; ++r) {
      int rowi = batch * NPTS + rowbase + g * 4 + r;
      size_t pi = (size_t)z * VECN + rowi;
      float lse = m[r] + flog2(fmaxf(s[r], 1e-38f));
      float val = -LN2 * lse;
      if (avg) {
        val = 0.5f * (val + pot[pi]);
        pot[pi] = val;
        Rarr[pi] = lse;
        nwout[(size_t)cjob * VECN + rowi].y = fmaf(val, IL2, lw2[rowi]);
      } else {
        fouts[pi] = val;
      }
    }
  }
}

// Iterations 1..10: fixed per-row normalizer R, full K, fused finalize epilogue.
__global__ __launch_bounds__(256, 8)
void extrap_fixed(const ushort* __restrict__ xb, const ushort* __restrict__ yb,
                  const float* __restrict__ nx2, const float* __restrict__ ny2,
                  const float2* __restrict__ nwin, float2* __restrict__ nwout,
                  const float* __restrict__ la2, const float* __restrict__ lb2,
                  float* __restrict__ pot, float* __restrict__ Rarr,
                  float* __restrict__ fouts, int avg) {
  __shared__ char vlds[2][CHUNK * 128];
  __shared__ char nwlds[2][CHUNK * 8];

  const int rb    = blockIdx.x;
  const int batch = blockIdx.y;
  const int z     = blockIdx.z;
  const ushort *U, *V; const float *nU2;
  switch (z) {
    case 0:  U = xb; V = xb; nU2 = nx2; break; // xx
    case 1:  U = yb; V = yb; nU2 = ny2; break; // yy
    case 2:  U = xb; V = yb; nU2 = nx2; break; // xy
    default: U = yb; V = xb; nU2 = ny2; break; // yx
  }
  const int lane = threadIdx.x & 63;
  const int w    = threadIdx.x >> 6;
  const int g    = lane >> 4;
  const int c    = lane & 15;
  const int rowbase = rb * 64 + w * 16;

  const ushort* Ub  = U + ((size_t)batch * NPTS + rowbase) * DIM;
  const char*   Vch = (const char*)(V + (size_t)batch * NPTS * DIM);
  const char*   nwch = (const char*)(nwin + (size_t)z * VECN + (size_t)batch * NPTS);

  bf16x8 a0 = *(const bf16x8*)(Ub + (size_t)c * DIM + g * 8);
  bf16x8 a1 = *(const bf16x8*)(Ub + (size_t)c * DIM + 32 + g * 8);

  float q[4], Rr[4];
  #pragma unroll
  for (int r = 0; r < 4; ++r) {
    size_t rowi = (size_t)batch * NPTS + rowbase + g * 4 + r;
    Rr[r] = Rarr[(size_t)z * VECN + rowi];
    q[r]  = -(nU2[rowi] + Rr[r]);        // -(norm_row + R_row), log2 units
  }

  const size_t lane_voff = ((size_t)(lane >> 3)) * 128
                         + (size_t)((((lane & 7) ^ (lane >> 3)) << 4));

  float s[4] = {0.f, 0.f, 0.f, 0.f};

  auto stage = [&](int p, int ck) {
    const char* gbase = Vch + (size_t)ck * CHUNK * 128;
    #pragma unroll
    for (int i = 0; i < 2; ++i) {
      int j = w * 2 + i;
      gload_lds16(gbase + (size_t)j * 1024 + lane_voff, &vlds[p][j * 1024]);
    }
    if (w == 0) {
      const char* gn = nwch + (size_t)ck * CHUNK * 8;
      gload_lds4(gn + lane * 4,       &nwlds[p][0]);
      gload_lds4(gn + 256 + lane * 4, &nwlds[p][256]);
    }
  };

  auto compute = [&](int p) {
    #pragma unroll
    for (int t = 0; t < 2; ++t) {
      const int rr0 = t * 32 + c;
      const int rr1 = rr0 + 16;
      const int x0 = (rr0 & 7) << 4;
      const char* pv0 = &vlds[p][rr0 * 128];
      const char* pv1 = &vlds[p][rr1 * 128];
      bf16x8 b0a = *(const bf16x8*)(pv0 + ((g * 16) ^ x0));
      bf16x8 b0b = *(const bf16x8*)(pv0 + ((64 + g * 16) ^ x0));
      bf16x8 b1a = *(const bf16x8*)(pv1 + ((g * 16) ^ x0));
      bf16x8 b1b = *(const bf16x8*)(pv1 + ((64 + g * 16) ^ x0));
      float2 nw0 = *(const float2*)&nwlds[p][rr0 * 8];
      float2 nw1 = *(const float2*)&nwlds[p][rr1 * 8];
      float ct0 = nw0.y - nw0.x;         // (pot+lw) - norm_col
      float ct1 = nw1.y - nw1.x;

      f32x4 acc0 = {0.f, 0.f, 0.f, 0.f}, acc1 = {0.f, 0.f, 0.f, 0.f};
      acc0 = __builtin_amdgcn_mfma_f32_16x16x32_bf16(a0, b0a, acc0, 0, 0, 0);
      acc0 = __builtin_amdgcn_mfma_f32_16x16x32_bf16(a1, b0b, acc0, 0, 0, 0);
      acc1 = __builtin_amdgcn_mfma_f32_16x16x32_bf16(a0, b1a, acc1, 0, 0, 0);
      acc1 = __builtin_amdgcn_mfma_f32_16x16x32_bf16(a1, b1b, acc1, 0, 0, 0);

      #pragma unroll
      for (int r = 0; r < 4; ++r) {
        s[r] += fexp2(fmaf(2.f * IL2, acc0[r], ct0 + q[r]));
        s[r] += fexp2(fmaf(2.f * IL2, acc1[r], ct1 + q[r]));
      }
    }
  };

  stage(0, 0);
  __syncthreads();
  int p = 0;
  for (int ck = 0; ck < NCHUNK; ++ck) {
    if (ck < NCHUNK - 1) stage(p ^ 1, ck + 1);
    compute(p);
    __syncthreads();
    p ^= 1;
  }

  #pragma unroll
  for (int r = 0; r < 4; ++r) {
    #pragma unroll
    for (int off = 1; off < 16; off <<= 1) s[r] += __shfl_xor(s[r], off);
  }
  if (c == 0) {
    const int cjob = z ^ (z >> 1);
    const float* lw2 = (z & 1) ? lb2 : la2;
    #pragma unroll
    for (int r = 0; r < 4; ++r) {
      int rowi = batch * NPTS + rowbase + g * 4 + r;
      size_t pi = (size_t)z * VECN + rowi;
      float lse = Rr[r] + flog2(fmaxf(s[r], 1e-38f));
      float val = -LN2 * lse;
      if (avg) {
        val = 0.5f * (val + pot[pi]);
        pot[pi] = val;
        Rarr[pi] = lse;
        nwout[(size_t)cjob * VECN + rowi].y = fmaf(val, IL2, lw2[rowi]);
      } else {
        fouts[pi] = val;
      }
    }
  }
}

// res = ( sum (ge-f)*a + sum (fe-g)*b ) / BATCH  -> single scalar
__global__ void reduce_kernel(const float* __restrict__ fouts,
                              const float* __restrict__ a, const float* __restrict__ b,
                              float* __restrict__ out) {
  const float* f  = fouts;
  const float* g  = fouts + (size_t)VECN;
  const float* ge = fouts + (size_t)2 * VECN;
  const float* fe = fouts + (size_t)3 * VECN;
  int tid = threadIdx.x;
  float acc = 0.f;
  for (int i = tid; i < VECN; i += 1024)
    acc += (ge[i] - f[i]) * a[i] + (fe[i] - g[i]) * b[i];
  #pragma unroll
  for (int off = 32; off; off >>= 1) acc += __shfl_xor(acc, off);
  __shared__ float red[16];
  if ((tid & 63) == 0) red[tid >> 6] = acc;
  __syncthreads();
  if (tid < 64) {
    float v = (tid < 16) ? red[tid] : 0.f;
    #pragma unroll
    for (int off = 8; off; off >>= 1) v += __shfl_xor(v, off);
    if (tid == 0) out[0] = v / (float)BATCH;
  }
}

extern "C" void kernel_launch(void* const* d_in, const int* in_sizes, int n_in,
                              void* d_out, int out_size, void* d_ws, size_t ws_size,
                              hipStream_t stream) {
  const float* x = (const float*)d_in[0];
  const float* a = (const float*)d_in[1];
  const float* y = (const float*)d_in[2];
  const float* b = (const float*)d_in[3];
  char* ws = (char*)d_ws;
  ushort* xb  = (ushort*)(ws + XB_OFF);
  ushort* yb  = (ushort*)(ws + YB_OFF);
  float* nx2  = (float*)(ws + NX2_OFF);
  float* ny2  = (float*)(ws + NY2_OFF);
  float* la2  = (float*)(ws + LA2_OFF);
  float* lb2  = (float*)(ws + LB2_OFF);
  float* pot  = (float*)(ws + POT_OFF);
  float2* nw0 = (float2*)(ws + NW0_OFF);
  float2* nw1 = (float2*)(ws + NW1_OFF);
  float* fouts= (float*)(ws + FOUT_OFF);
  float* Rarr = (float*)(ws + R_OFF);

  prep_convert<<<dim3(2 * VECN / 4), 256, 0, stream>>>(x, y, xb, yb, nx2, ny2);
  prep_vecs<<<dim3(VECN / 256), 256, 0, stream>>>(a, b, nx2, ny2, la2, lb2, pot, nw0, nw1);

  const dim3 eg(NPTS / 64, BATCH, 4);   // 32 x 8 x 4 = 1024 blocks
  float2* bufs[2] = {nw0, nw1};
  // iteration 0: online-max (safe, seeds R); reads nw0, writes nw1
  extrap_online<<<eg, 256, 0, stream>>>(xb, yb, nx2, ny2, bufs[0], bufs[1],
                                        la2, lb2, pot, Rarr, fouts, 1);
  // iterations 1..9: fixed-R fast path (ping-pong nw)
  for (int it = 1; it < 10; ++it) {
    extrap_fixed<<<eg, 256, 0, stream>>>(xb, yb, nx2, ny2,
                                         bufs[it & 1], bufs[(it & 1) ^ 1],
                                         la2, lb2, pot, Rarr, fouts, 1);
  }
  // final extrapolation (no averaging) -> f, g, ge, fe
  extrap_fixed<<<eg, 256, 0, stream>>>(xb, yb, nx2, ny2,
                                       bufs[10 & 1], bufs[(10 & 1) ^ 1],
                                       la2, lb2, pot, Rarr, fouts, 0);

  reduce_kernel<<<1, 1024, 0, stream>>>(fouts, a, b, (float*)d_out);
}

// Round 14
// 478.779 us; speedup vs baseline: 1.0561x; 1.0561x over previous
//
#include <hip/hip_runtime.h>
#include <stdint.h>

// Problem constants (fixed by setup_inputs): B=8, L=K=2048, D=64
#define BATCH 8
#define NPTS  2048
#define DIM   64
#define VECN  (BATCH*NPTS)   // 16384
#define CHUNK 256            // columns staged per LDS buffer
#define NCHUNK (NPTS/CHUNK)  // 8 (full K per block)

typedef __attribute__((ext_vector_type(8))) short bf16x8;
typedef __attribute__((ext_vector_type(4))) float f32x4;

#define IL2 1.4426950408889634f
#define LN2 0.6931471805599453f

__device__ inline float fexp2(float x) { return __builtin_amdgcn_exp2f(x); }
__device__ inline float flog2(float x) { return __builtin_amdgcn_logf(x); }

// async global->LDS staging (lds dest = uniform base + lane*size; global src per-lane)
__device__ inline void gload_lds16(const void* g, void* l) {
  __builtin_amdgcn_global_load_lds(
      (const __attribute__((address_space(1))) uint32_t*)g,
      (__attribute__((address_space(3))) uint32_t*)l, 16, 0, 0);
}

// ---- workspace layout (bytes) ----
static constexpr size_t XB_OFF   = 0;                                   // bf16 x : 2 MB
static constexpr size_t YB_OFF   = (size_t)VECN * DIM * 2;              // bf16 y : 2 MB
static constexpr size_t NX2_OFF  = YB_OFF * 2;                          // ||x||^2 * IL2
static constexpr size_t NY2_OFF  = NX2_OFF + (size_t)VECN * 4;
static constexpr size_t LA2_OFF  = NY2_OFF + (size_t)VECN * 4;          // log2(a)
static constexpr size_t LB2_OFF  = LA2_OFF + (size_t)VECN * 4;          // log2(b)
static constexpr size_t POT_OFF  = LB2_OFF + (size_t)VECN * 4;          // 4 pots
static constexpr size_t NW0_OFF  = POT_OFF + (size_t)4 * VECN * 4;      // nw ping [4][VECN] float2
static constexpr size_t NW1_OFF  = NW0_OFF + (size_t)4 * VECN * 8;      // nw pong
static constexpr size_t FOUT_OFF = NW1_OFF + (size_t)4 * VECN * 8;      // f,g,ge,fe
static constexpr size_t R_OFF    = FOUT_OFF + (size_t)4 * VECN * 4;     // per-row lse (log2) [4][VECN]

__device__ inline ushort f2bf(float f) {
  uint32_t u = __float_as_uint(f);
  u += 0x7fffu + ((u >> 16) & 1u);   // RNE
  return (ushort)(u >> 16);
}

// One wave per row: convert to bf16 + exact f32 squared norm (scaled by IL2).
__global__ void prep_convert(const float* __restrict__ x, const float* __restrict__ y,
                             ushort* __restrict__ xb, ushort* __restrict__ yb,
                             float* __restrict__ nx2, float* __restrict__ ny2) {
  int wid  = (blockIdx.x * blockDim.x + threadIdx.x) >> 6;
  int lane = threadIdx.x & 63;
  const float* src; ushort* dst; float* nrm; int row;
  if (wid < VECN) { src = x; dst = xb; nrm = nx2; row = wid; }
  else            { src = y; dst = yb; nrm = ny2; row = wid - VECN; }
  float v = src[(size_t)row * DIM + lane];
  dst[(size_t)row * DIM + lane] = f2bf(v);
  float sq = v * v;
  #pragma unroll
  for (int off = 32; off; off >>= 1) sq += __shfl_xor(sq, off);
  if (lane == 0) nrm[row] = sq * IL2;
}

// log2-weights, zero pots, init BOTH nw buffers = {V-side norm, V-side log2 weight}
__global__ void prep_vecs(const float* __restrict__ a, const float* __restrict__ b,
                          const float* __restrict__ nx2, const float* __restrict__ ny2,
                          float* __restrict__ la2, float* __restrict__ lb2,
                          float* __restrict__ pot,
                          float2* __restrict__ nw0, float2* __restrict__ nw1) {
  int i = blockIdx.x * blockDim.x + threadIdx.x;
  float l2a = log2f(a[i]);
  float l2b = log2f(b[i]);
  la2[i] = l2a;
  lb2[i] = l2b;
  float nxv = nx2[i], nyv = ny2[i];
  float2 vx = make_float2(nxv, l2a), vy = make_float2(nyv, l2b);
  nw0[i]                    = vx;  nw1[i]                    = vx;  // z0 xx: V=x
  nw0[(size_t)VECN + i]     = vy;  nw1[(size_t)VECN + i]     = vy;  // z1 yy: V=y
  nw0[(size_t)2*VECN + i]   = vy;  nw1[(size_t)2*VECN + i]   = vy;  // z2 xy: V=y
  nw0[(size_t)3*VECN + i]   = vx;  nw1[(size_t)3*VECN + i]   = vx;  // z3 yx: V=x
  #pragma unroll
  for (int j = 0; j < 4; ++j) pot[(size_t)j * VECN + i] = 0.f;
}

// ---- paired extrap kernels: one block computes BOTH jobs sharing V columns ----
// pair 0: zA=0 (xx: U=x), zB=3 (yx: U=y), V=x.  pair 1: zA=1 (yy: U=y), zB=2 (xy: U=x), V=y.
// grid: (NPTS/64, BATCH, 2); block 256 (4 waves, 16 rows per job each)

// Iteration-0: online-max (safe, seeds R), fused finalize.
__global__ __launch_bounds__(256, 2)
void extrap_online(const ushort* __restrict__ xb, const ushort* __restrict__ yb,
                   const float* __restrict__ nx2, const float* __restrict__ ny2,
                   const float2* __restrict__ nwin, float2* __restrict__ nwout,
                   const float* __restrict__ la2, const float* __restrict__ lb2,
                   float* __restrict__ pot, float* __restrict__ Rarr,
                   float* __restrict__ fouts, int avg) {
  __shared__ char vlds[2][CHUNK * 128];      // 2 x 32 KB, swizzled V rows
  __shared__ char nwlds[2][2][CHUNK * 8];    // 2 buf x 2 jobs x 2 KB, linear float2

  const int rb    = blockIdx.x;
  const int batch = blockIdx.y;
  const int pair  = blockIdx.z;
  const int zA = pair ? 1 : 0, zB = pair ? 2 : 3;
  const ushort* V  = pair ? yb : xb;
  const ushort* UA = pair ? yb : xb;
  const ushort* UB = pair ? xb : yb;
  const float* nUA = pair ? ny2 : nx2;
  const float* nUB = pair ? nx2 : ny2;

  const int lane = threadIdx.x & 63;
  const int w    = threadIdx.x >> 6;
  const int g    = lane >> 4;
  const int c    = lane & 15;
  const int rowbase = rb * 64 + w * 16;

  const ushort* UbA = UA + ((size_t)batch * NPTS + rowbase) * DIM;
  const ushort* UbB = UB + ((size_t)batch * NPTS + rowbase) * DIM;
  const char*   Vch = (const char*)(V + (size_t)batch * NPTS * DIM);   // 128B rows
  const char*   nwchA = (const char*)(nwin + (size_t)zA * VECN + (size_t)batch * NPTS);
  const char*   nwchB = (const char*)(nwin + (size_t)zB * VECN + (size_t)batch * NPTS);

  bf16x8 aA0 = *(const bf16x8*)(UbA + (size_t)c * DIM + g * 8);
  bf16x8 aA1 = *(const bf16x8*)(UbA + (size_t)c * DIM + 32 + g * 8);
  bf16x8 aB0 = *(const bf16x8*)(UbB + (size_t)c * DIM + g * 8);
  bf16x8 aB1 = *(const bf16x8*)(UbB + (size_t)c * DIM + 32 + g * 8);

  float nxA[4], nxB[4];
  #pragma unroll
  for (int r = 0; r < 4; ++r) {
    size_t rowi = (size_t)batch * NPTS + rowbase + g * 4 + r;
    nxA[r] = nUA[rowi];
    nxB[r] = nUB[rowi];
  }

  // slab-local pre-swizzled staging offset (1 KB slab = 8 rows of 128 B)
  const size_t lane_voff = ((size_t)(lane >> 3)) * 128
                         + (size_t)((((lane & 7) ^ (lane >> 3)) << 4));

  float mA[4], sA[4], mB[4], sB[4];
  #pragma unroll
  for (int r = 0; r < 4; ++r) {
    mA[r] = -INFINITY; sA[r] = 0.f;
    mB[r] = -INFINITY; sB[r] = 0.f;
  }

  auto stage = [&](int p, int ck) {
    const char* gbase = Vch + (size_t)ck * CHUNK * 128;
    #pragma unroll
    for (int i = 0; i < 8; ++i) {
      int j = w * 8 + i;                                  // 1 KB slab
      gload_lds16(gbase + (size_t)j * 1024 + lane_voff, &vlds[p][j * 1024]);
    }
    if (w == 0) {   // nwA: 2 KB linear
      const char* gn = nwchA + (size_t)ck * CHUNK * 8;
      gload_lds16(gn + lane * 16,        &nwlds[p][0][0]);
      gload_lds16(gn + 1024 + lane * 16, &nwlds[p][0][1024]);
    }
    if (w == 1) {   // nwB: 2 KB linear
      const char* gn = nwchB + (size_t)ck * CHUNK * 8;
      gload_lds16(gn + lane * 16,        &nwlds[p][1][0]);
      gload_lds16(gn + 1024 + lane * 16, &nwlds[p][1][1024]);
    }
  };

  auto compute = [&](int p) {
    #pragma unroll
    for (int t = 0; t < 8; ++t) {
      const int rr0 = t * 32 + c;
      const int rr1 = rr0 + 16;
      const int x0 = (rr0 & 7) << 4;           // rr1&7 == rr0&7
      const char* pv0 = &vlds[p][rr0 * 128];
      const char* pv1 = &vlds[p][rr1 * 128];
      bf16x8 b0a = *(const bf16x8*)(pv0 + ((g * 16) ^ x0));
      bf16x8 b0b = *(const bf16x8*)(pv0 + ((64 + g * 16) ^ x0));
      bf16x8 b1a = *(const bf16x8*)(pv1 + ((g * 16) ^ x0));
      bf16x8 b1b = *(const bf16x8*)(pv1 + ((64 + g * 16) ^ x0));
      float2 nwA0 = *(const float2*)&nwlds[p][0][rr0 * 8];
      float2 nwA1 = *(const float2*)&nwlds[p][0][rr1 * 8];
      float2 nwB0 = *(const float2*)&nwlds[p][1][rr0 * 8];
      float2 nwB1 = *(const float2*)&nwlds[p][1][rr1 * 8];

      {
        f32x4 acc0 = {0.f, 0.f, 0.f, 0.f}, acc1 = {0.f, 0.f, 0.f, 0.f};
        acc0 = __builtin_amdgcn_mfma_f32_16x16x32_bf16(aA0, b0a, acc0, 0, 0, 0);
        acc0 = __builtin_amdgcn_mfma_f32_16x16x32_bf16(aA1, b0b, acc0, 0, 0, 0);
        acc1 = __builtin_amdgcn_mfma_f32_16x16x32_bf16(aA0, b1a, acc1, 0, 0, 0);
        acc1 = __builtin_amdgcn_mfma_f32_16x16x32_bf16(aA1, b1b, acc1, 0, 0, 0);
        #pragma unroll
        for (int r = 0; r < 4; ++r) {
          float d0 = fmaxf(fmaf(-2.f * IL2, acc0[r], nxA[r] + nwA0.x), 0.f);
          float d1 = fmaxf(fmaf(-2.f * IL2, acc1[r], nxA[r] + nwA1.x), 0.f);
          float t0 = nwA0.y - d0;
          float t1 = nwA1.y - d1;
          float mn = fmaxf(mA[r], fmaxf(t0, t1));
          sA[r] = fmaf(sA[r], fexp2(mA[r] - mn), fexp2(t0 - mn) + fexp2(t1 - mn));
          mA[r] = mn;
        }
      }
      {
        f32x4 acc0 = {0.f, 0.f, 0.f, 0.f}, acc1 = {0.f, 0.f, 0.f, 0.f};
        acc0 = __builtin_amdgcn_mfma_f32_16x16x32_bf16(aB0, b0a, acc0, 0, 0, 0);
        acc0 = __builtin_amdgcn_mfma_f32_16x16x32_bf16(aB1, b0b, acc0, 0, 0, 0);
        acc1 = __builtin_amdgcn_mfma_f32_16x16x32_bf16(aB0, b1a, acc1, 0, 0, 0);
        acc1 = __builtin_amdgcn_mfma_f32_16x16x32_bf16(aB1, b1b, acc1, 0, 0, 0);
        #pragma unroll
        for (int r = 0; r < 4; ++r) {
          float d0 = fmaxf(fmaf(-2.f * IL2, acc0[r], nxB[r] + nwB0.x), 0.f);
          float d1 = fmaxf(fmaf(-2.f * IL2, acc1[r], nxB[r] + nwB1.x), 0.f);
          float t0 = nwB0.y - d0;
          float t1 = nwB1.y - d1;
          float mn = fmaxf(mB[r], fmaxf(t0, t1));
          sB[r] = fmaf(sB[r], fexp2(mB[r] - mn), fexp2(t0 - mn) + fexp2(t1 - mn));
          mB[r] = mn;
        }
      }
    }
  };

  stage(0, 0);
  __syncthreads();
  int p = 0;
  for (int ck = 0; ck < NCHUNK; ++ck) {
    if (ck < NCHUNK - 1) stage(p ^ 1, ck + 1);   // prefetch in flight during compute
    compute(p);
    __syncthreads();
    p ^= 1;
  }

  #pragma unroll
  for (int r = 0; r < 4; ++r) {
    #pragma unroll
    for (int off = 1; off < 16; off <<= 1) {
      float mo = __shfl_xor(mA[r], off);
      float so = __shfl_xor(sA[r], off);
      float mn = fmaxf(mA[r], mo);
      sA[r] = fmaf(sA[r], fexp2(mA[r] - mn), so * fexp2(mo - mn));
      mA[r] = mn;
      mo = __shfl_xor(mB[r], off);
      so = __shfl_xor(sB[r], off);
      mn = fmaxf(mB[r], mo);
      sB[r] = fmaf(sB[r], fexp2(mB[r] - mn), so * fexp2(mo - mn));
      mB[r] = mn;
    }
  }
  if (c == 0) {
    const int cjobA = zA ^ (zA >> 1);
    const int cjobB = zB ^ (zB >> 1);
    const float* lwA = (zA & 1) ? lb2 : la2;
    const float* lwB = (zB & 1) ? lb2 : la2;
    #pragma unroll
    for (int r = 0; r < 4; ++r) {
      int rowi = batch * NPTS + rowbase + g * 4 + r;
      size_t piA = (size_t)zA * VECN + rowi;
      size_t piB = (size_t)zB * VECN + rowi;
      float lseA = mA[r] + flog2(fmaxf(sA[r], 1e-38f));
      float lseB = mB[r] + flog2(fmaxf(sB[r], 1e-38f));
      float valA = -LN2 * lseA;
      float valB = -LN2 * lseB;
      if (avg) {
        valA = 0.5f * (valA + pot[piA]);
        pot[piA] = valA;
        Rarr[piA] = lseA;
        nwout[(size_t)cjobA * VECN + rowi].y = fmaf(valA, IL2, lwA[rowi]);
        valB = 0.5f * (valB + pot[piB]);
        pot[piB] = valB;
        Rarr[piB] = lseB;
        nwout[(size_t)cjobB * VECN + rowi].y = fmaf(valB, IL2, lwB[rowi]);
      } else {
        fouts[piA] = valA;
        fouts[piB] = valB;
      }
    }
  }
}

// Iterations 1..10: fixed per-row normalizer R (1 exp2/entry), paired, fused finalize.
__global__ __launch_bounds__(256, 2)
void extrap_fixed(const ushort* __restrict__ xb, const ushort* __restrict__ yb,
                  const float* __restrict__ nx2, const float* __restrict__ ny2,
                  const float2* __restrict__ nwin, float2* __restrict__ nwout,
                  const float* __restrict__ la2, const float* __restrict__ lb2,
                  float* __restrict__ pot, float* __restrict__ Rarr,
                  float* __restrict__ fouts, int avg) {
  __shared__ char vlds[2][CHUNK * 128];
  __shared__ char nwlds[2][2][CHUNK * 8];

  const int rb    = blockIdx.x;
  const int batch = blockIdx.y;
  const int pair  = blockIdx.z;
  const int zA = pair ? 1 : 0, zB = pair ? 2 : 3;
  const ushort* V  = pair ? yb : xb;
  const ushort* UA = pair ? yb : xb;
  const ushort* UB = pair ? xb : yb;
  const float* nUA = pair ? ny2 : nx2;
  const float* nUB = pair ? nx2 : ny2;

  const int lane = threadIdx.x & 63;
  const int w    = threadIdx.x >> 6;
  const int g    = lane >> 4;
  const int c    = lane & 15;
  const int rowbase = rb * 64 + w * 16;

  const ushort* UbA = UA + ((size_t)batch * NPTS + rowbase) * DIM;
  const ushort* UbB = UB + ((size_t)batch * NPTS + rowbase) * DIM;
  const char*   Vch = (const char*)(V + (size_t)batch * NPTS * DIM);
  const char*   nwchA = (const char*)(nwin + (size_t)zA * VECN + (size_t)batch * NPTS);
  const char*   nwchB = (const char*)(nwin + (size_t)zB * VECN + (size_t)batch * NPTS);

  bf16x8 aA0 = *(const bf16x8*)(UbA + (size_t)c * DIM + g * 8);
  bf16x8 aA1 = *(const bf16x8*)(UbA + (size_t)c * DIM + 32 + g * 8);
  bf16x8 aB0 = *(const bf16x8*)(UbB + (size_t)c * DIM + g * 8);
  bf16x8 aB1 = *(const bf16x8*)(UbB + (size_t)c * DIM + 32 + g * 8);

  float qA[4], RrA[4], qB[4], RrB[4];
  #pragma unroll
  for (int r = 0; r < 4; ++r) {
    size_t rowi = (size_t)batch * NPTS + rowbase + g * 4 + r;
    RrA[r] = Rarr[(size_t)zA * VECN + rowi];
    qA[r]  = -(nUA[rowi] + RrA[r]);
    RrB[r] = Rarr[(size_t)zB * VECN + rowi];
    qB[r]  = -(nUB[rowi] + RrB[r]);
  }

  const size_t lane_voff = ((size_t)(lane >> 3)) * 128
                         + (size_t)((((lane & 7) ^ (lane >> 3)) << 4));

  float sA[4] = {0.f, 0.f, 0.f, 0.f};
  float sB[4] = {0.f, 0.f, 0.f, 0.f};

  auto stage = [&](int p, int ck) {
    const char* gbase = Vch + (size_t)ck * CHUNK * 128;
    #pragma unroll
    for (int i = 0; i < 8; ++i) {
      int j = w * 8 + i;
      gload_lds16(gbase + (size_t)j * 1024 + lane_voff, &vlds[p][j * 1024]);
    }
    if (w == 0) {
      const char* gn = nwchA + (size_t)ck * CHUNK * 8;
      gload_lds16(gn + lane * 16,        &nwlds[p][0][0]);
      gload_lds16(gn + 1024 + lane * 16, &nwlds[p][0][1024]);
    }
    if (w == 1) {
      const char* gn = nwchB + (size_t)ck * CHUNK * 8;
      gload_lds16(gn + lane * 16,        &nwlds[p][1][0]);
      gload_lds16(gn + 1024 + lane * 16, &nwlds[p][1][1024]);
    }
  };

  auto compute = [&](int p) {
    #pragma unroll
    for (int t = 0; t < 8; ++t) {
      const int rr0 = t * 32 + c;
      const int rr1 = rr0 + 16;
      const int x0 = (rr0 & 7) << 4;
      const char* pv0 = &vlds[p][rr0 * 128];
      const char* pv1 = &vlds[p][rr1 * 128];
      bf16x8 b0a = *(const bf16x8*)(pv0 + ((g * 16) ^ x0));
      bf16x8 b0b = *(const bf16x8*)(pv0 + ((64 + g * 16) ^ x0));
      bf16x8 b1a = *(const bf16x8*)(pv1 + ((g * 16) ^ x0));
      bf16x8 b1b = *(const bf16x8*)(pv1 + ((64 + g * 16) ^ x0));
      float2 nwA0 = *(const float2*)&nwlds[p][0][rr0 * 8];
      float2 nwA1 = *(const float2*)&nwlds[p][0][rr1 * 8];
      float2 nwB0 = *(const float2*)&nwlds[p][1][rr0 * 8];
      float2 nwB1 = *(const float2*)&nwlds[p][1][rr1 * 8];
      float ctA0 = nwA0.y - nwA0.x, ctA1 = nwA1.y - nwA1.x;
      float ctB0 = nwB0.y - nwB0.x, ctB1 = nwB1.y - nwB1.x;

      {
        f32x4 acc0 = {0.f, 0.f, 0.f, 0.f}, acc1 = {0.f, 0.f, 0.f, 0.f};
        acc0 = __builtin_amdgcn_mfma_f32_16x16x32_bf16(aA0, b0a, acc0, 0, 0, 0);
        acc0 = __builtin_amdgcn_mfma_f32_16x16x32_bf16(aA1, b0b, acc0, 0, 0, 0);
        acc1 = __builtin_amdgcn_mfma_f32_16x16x32_bf16(aA0, b1a, acc1, 0, 0, 0);
        acc1 = __builtin_amdgcn_mfma_f32_16x16x32_bf16(aA1, b1b, acc1, 0, 0, 0);
        #pragma unroll
        for (int r = 0; r < 4; ++r) {
          sA[r] += fexp2(fmaf(2.f * IL2, acc0[r], ctA0 + qA[r]));
          sA[r] += fexp2(fmaf(2.f * IL2, acc1[r], ctA1 + qA[r]));
        }
      }
      {
        f32x4 acc0 = {0.f, 0.f, 0.f, 0.f}, acc1 = {0.f, 0.f, 0.f, 0.f};
        acc0 = __builtin_amdgcn_mfma_f32_16x16x32_bf16(aB0, b0a, acc0, 0, 0, 0);
        acc0 = __builtin_amdgcn_mfma_f32_16x16x32_bf16(aB1, b0b, acc0, 0, 0, 0);
        acc1 = __builtin_amdgcn_mfma_f32_16x16x32_bf16(aB0, b1a, acc1, 0, 0, 0);
        acc1 = __builtin_amdgcn_mfma_f32_16x16x32_bf16(aB1, b1b, acc1, 0, 0, 0);
        #pragma unroll
        for (int r = 0; r < 4; ++r) {
          sB[r] += fexp2(fmaf(2.f * IL2, acc0[r], ctB0 + qB[r]));
          sB[r] += fexp2(fmaf(2.f * IL2, acc1[r], ctB1 + qB[r]));
        }
      }
    }
  };

  stage(0, 0);
  __syncthreads();
  int p = 0;
  for (int ck = 0; ck < NCHUNK; ++ck) {
    if (ck < NCHUNK - 1) stage(p ^ 1, ck + 1);
    compute(p);
    __syncthreads();
    p ^= 1;
  }

  #pragma unroll
  for (int r = 0; r < 4; ++r) {
    #pragma unroll
    for (int off = 1; off < 16; off <<= 1) {
      sA[r] += __shfl_xor(sA[r], off);
      sB[r] += __shfl_xor(sB[r], off);
    }
  }
  if (c == 0) {
    const int cjobA = zA ^ (zA >> 1);
    const int cjobB = zB ^ (zB >> 1);
    const float* lwA = (zA & 1) ? lb2 : la2;
    const float* lwB = (zB & 1) ? lb2 : la2;
    #pragma unroll
    for (int r = 0; r < 4; ++r) {
      int rowi = batch * NPTS + rowbase + g * 4 + r;
      size_t piA = (size_t)zA * VECN + rowi;
      size_t piB = (size_t)zB * VECN + rowi;
      float lseA = RrA[r] + flog2(fmaxf(sA[r], 1e-38f));
      float lseB = RrB[r] + flog2(fmaxf(sB[r], 1e-38f));
      float valA = -LN2 * lseA;
      float valB = -LN2 * lseB;
      if (avg) {
        valA = 0.5f * (valA + pot[piA]);
        pot[piA] = valA;
        Rarr[piA] = lseA;
        nwout[(size_t)cjobA * VECN + rowi].y = fmaf(valA, IL2, lwA[rowi]);
        valB = 0.5f * (valB + pot[piB]);
        pot[piB] = valB;
        Rarr[piB] = lseB;
        nwout[(size_t)cjobB * VECN + rowi].y = fmaf(valB, IL2, lwB[rowi]);
      } else {
        fouts[piA] = valA;
        fouts[piB] = valB;
      }
    }
  }
}

// res = ( sum (ge-f)*a + sum (fe-g)*b ) / BATCH  -> single scalar
__global__ void reduce_kernel(const float* __restrict__ fouts,
                              const float* __restrict__ a, const float* __restrict__ b,
                              float* __restrict__ out) {
  const float* f  = fouts;
  const float* g  = fouts + (size_t)VECN;
  const float* ge = fouts + (size_t)2 * VECN;
  const float* fe = fouts + (size_t)3 * VECN;
  int tid = threadIdx.x;
  float acc = 0.f;
  for (int i = tid; i < VECN; i += 1024)
    acc += (ge[i] - f[i]) * a[i] + (fe[i] - g[i]) * b[i];
  #pragma unroll
  for (int off = 32; off; off >>= 1) acc += __shfl_xor(acc, off);
  __shared__ float red[16];
  if ((tid & 63) == 0) red[tid >> 6] = acc;
  __syncthreads();
  if (tid < 64) {
    float v = (tid < 16) ? red[tid] : 0.f;
    #pragma unroll
    for (int off = 8; off; off >>= 1) v += __shfl_xor(v, off);
    if (tid == 0) out[0] = v / (float)BATCH;
  }
}

extern "C" void kernel_launch(void* const* d_in, const int* in_sizes, int n_in,
                              void* d_out, int out_size, void* d_ws, size_t ws_size,
                              hipStream_t stream) {
  const float* x = (const float*)d_in[0];
  const float* a = (const float*)d_in[1];
  const float* y = (const float*)d_in[2];
  const float* b = (const float*)d_in[3];
  char* ws = (char*)d_ws;
  ushort* xb  = (ushort*)(ws + XB_OFF);
  ushort* yb  = (ushort*)(ws + YB_OFF);
  float* nx2  = (float*)(ws + NX2_OFF);
  float* ny2  = (float*)(ws + NY2_OFF);
  float* la2  = (float*)(ws + LA2_OFF);
  float* lb2  = (float*)(ws + LB2_OFF);
  float* pot  = (float*)(ws + POT_OFF);
  float2* nw0 = (float2*)(ws + NW0_OFF);
  float2* nw1 = (float2*)(ws + NW1_OFF);
  float* fouts= (float*)(ws + FOUT_OFF);
  float* Rarr = (float*)(ws + R_OFF);

  prep_convert<<<dim3(2 * VECN / 4), 256, 0, stream>>>(x, y, xb, yb, nx2, ny2);
  prep_vecs<<<dim3(VECN / 256), 256, 0, stream>>>(a, b, nx2, ny2, la2, lb2, pot, nw0, nw1);

  const dim3 eg(NPTS / 64, BATCH, 2);   // 32 x 8 x 2 = 512 blocks
  float2* bufs[2] = {nw0, nw1};
  // iteration 0: online-max (safe, seeds R); reads nw0, writes nw1
  extrap_online<<<eg, 256, 0, stream>>>(xb, yb, nx2, ny2, bufs[0], bufs[1],
                                        la2, lb2, pot, Rarr, fouts, 1);
  // iterations 1..9: fixed-R fast path (ping-pong nw)
  for (int it = 1; it < 10; ++it) {
    extrap_fixed<<<eg, 256, 0, stream>>>(xb, yb, nx2, ny2,
                                         bufs[it & 1], bufs[(it & 1) ^ 1],
                                         la2, lb2, pot, Rarr, fouts, 1);
  }
  // final extrapolation (no averaging) -> f, g, ge, fe
  extrap_fixed<<<eg, 256, 0, stream>>>(xb, yb, nx2, ny2,
                                       bufs[10 & 1], bufs[(10 & 1) ^ 1],
                                       la2, lb2, pot, Rarr, fouts, 0);

  reduce_kernel<<<1, 1024, 0, stream>>>(fouts, a, b, (float*)d_out);
}